// Round 6
// baseline (1063.579 us; speedup 1.0000x reference)
//
#include <hip/hip_runtime.h>
#include <hip/hip_cooperative_groups.h>

namespace cg = cooperative_groups;

#define NEG_SLOPE 0.2f
#define RSHIFT 9               // range width 512 dst nodes
#define RW     512
#define CHUNKP 2048            // edges per partition item

__device__ __forceinline__ ushort f2bf(float f) {
    union { float f; unsigned u; } c; c.f = f;
    unsigned u = c.u;
    return (ushort)((u + 0x7fffu + ((u >> 16) & 1u)) >> 16);   // RNE
}

// One cooperative kernel, 4 phases separated by grid syncs:
//  A: out[:, :128]=x + xbf=bf16(x) | scores (su,sv) | gcur zero
//  B: partition edges -> per-(set,range) (dst<<16|src) segments (read-once)
//  C: per-range LDS counting-sort -> CSR off[] + ushort bucket[]
//  D: per-node single-pass softmax + gather-aggregate
__global__ __launch_bounds__(256, 8) void fused_kernel(
    const float* __restrict__ x, const float* __restrict__ wu,
    const float* __restrict__ bu, const float* __restrict__ wv,
    const int* __restrict__ s0, const int* __restrict__ d0,
    const int* __restrict__ s1, const int* __restrict__ d1,
    float* __restrict__ out, ushort* __restrict__ xbf,
    float* __restrict__ su, float* __restrict__ sv,
    int* __restrict__ gcur, unsigned* __restrict__ pairs,
    ushort* __restrict__ bucket, int* __restrict__ off,
    int N, int E, int nr, int cap,
    int convItems, int scoreItems, int partItems, int buildItems, int aggItems)
{
    cg::grid_group grid = cg::this_grid();
    __shared__ __align__(16) float smem[4224];   // scores w / build sort / agg evals
    __shared__ int misc[8];
    int* smi = (int*)smem;
    const int tid = threadIdx.x;
    const int nb = gridDim.x;
    const int bid = blockIdx.x;

    // ================= phase A =================
    if (bid == 0) for (int i = tid; i < 2 * nr; i += 256) gcur[i] = 0;
    int a1 = convItems + scoreItems;
    for (int v = bid; v < a1; v += nb) {
        if (v < convItems) {                      // ---- copy + bf16 convert
            int base = v * 2048 + tid;
#pragma unroll
            for (int j = 0; j < 8; ++j) {
                int i = base + j * 256;
                if (i < N * 32) {
                    float4 val = ((const float4*)x)[i];
                    int n = i >> 5, q = i & 31;
                    ((float4*)out)[(size_t)n * 96 + q] = val;
                    ushort4 b;
                    b.x = f2bf(val.x); b.y = f2bf(val.y);
                    b.z = f2bf(val.z); b.w = f2bf(val.w);
                    *(ushort4*)(xbf + (size_t)i * 4) = b;
                }
            }
        } else {                                  // ---- scores (128 nodes/item)
            int nbase = (v - convItems) * 128;
            for (int i = tid; i < 4096; i += 256) {
                int o = i >> 7, k = i & 127;
                smem[o * 132 + k] = (o < 16) ? wu[i] : wv[i - 2048];
            }
            __syncthreads();
            int o = tid & 15;
            const float* wur = smem + o * 132;          // float4-readable, 2-way
            const float* wvr = smem + (16 + o) * 132;   // bank alias = free
            for (int sub = 0; sub < 8; ++sub) {
                int n = nbase + sub * 16 + (tid >> 4);
                if (n < N) {
                    const float4* xr4 = (const float4*)(x + (size_t)n * 128);
                    float au = 0.f, av = 0.f;
#pragma unroll
                    for (int kk = 0; kk < 32; ++kk) {
                        float4 xv = xr4[kk];
                        float4 a4 = *(const float4*)(wur + kk * 4);
                        float4 b4 = *(const float4*)(wvr + kk * 4);
                        au = fmaf(xv.x, a4.x, au);  av = fmaf(xv.x, b4.x, av);
                        au = fmaf(xv.y, a4.y, au);  av = fmaf(xv.y, b4.y, av);
                        au = fmaf(xv.z, a4.z, au);  av = fmaf(xv.z, b4.z, av);
                        au = fmaf(xv.w, a4.w, au);  av = fmaf(xv.w, b4.w, av);
                    }
                    su[n * 16 + o] = au + bu[o];
                    sv[n * 16 + o] = av;
                }
            }
            __syncthreads();
        }
    }
    __threadfence();
    grid.sync();

    // ================= phase B: partition =================
    int ppset = partItems >> 1;
    for (int v = bid; v < partItems; v += nb) {
        int t = v / ppset, c = v % ppset;
        const int* ss = t ? s1 : s0;
        const int* dd = t ? d1 : d0;
        int beg = c * CHUNKP, end = min(E, beg + CHUNKP);
        int* lcnt = smi; int* gb = smi + 128; int* lrun = smi + 256;
        if (tid < nr) lcnt[tid] = 0;
        __syncthreads();
        for (int e = beg + tid; e < end; e += 256)
            atomicAdd(&lcnt[dd[e] >> RSHIFT], 1);
        __syncthreads();
        if (tid < nr) {
            gb[tid] = atomicAdd(&gcur[t * nr + tid], lcnt[tid]);
            lrun[tid] = 0;
        }
        __syncthreads();
        unsigned* pt = pairs + (size_t)t * nr * cap;
        for (int e = beg + tid; e < end; e += 256) {
            int dst = dd[e], src = ss[e];
            int r = dst >> RSHIFT;
            int pos = atomicAdd(&lrun[r], 1);
            pt[(size_t)r * cap + gb[r] + pos] = ((unsigned)dst << 16) | (unsigned)src;
        }
        __syncthreads();
    }
    __threadfence();
    grid.sync();

    // ================= phase C: build CSR =================
    for (int v = bid; v < buildItems; v += nb) {
        int r = v % nr, t = v / nr;
        int m = gcur[t * nr + r];
        int s = (tid < r) ? gcur[t * nr + tid] : 0;   // base = edges in earlier ranges
#pragma unroll
        for (int d = 1; d < 64; d <<= 1) s += __shfl_xor(s, d);
        if ((tid & 63) == 0) misc[tid >> 6] = s;
        int* hist = smi; int* scanb = smi + 512;
        hist[2 * tid] = 0; hist[2 * tid + 1] = 0;
        __syncthreads();
        int base = misc[0] + misc[1] + misc[2] + misc[3];
        const unsigned* p = pairs + ((size_t)t * nr + r) * cap;
        for (int i = tid; i < m; i += 256)
            atomicAdd(&hist[(p[i] >> 16) & (RW - 1)], 1);
        __syncthreads();
        int h0 = hist[2 * tid], h1 = hist[2 * tid + 1], tot = h0 + h1;
        scanb[tid] = tot;
        __syncthreads();
        int incl = tot;
        for (int d = 1; d < 256; d <<= 1) {
            int add = (tid >= d) ? scanb[tid - d] : 0;
            __syncthreads();
            incl += add; scanb[tid] = incl;
            __syncthreads();
        }
        int e0 = incl - tot, e1 = e0 + h0;
        int lo = r << RSHIFT;
        int* offt = off + (size_t)t * (N + 1);
        if (lo + 2 * tid < N)     offt[lo + 2 * tid]     = base + e0;
        if (lo + 2 * tid + 1 < N) offt[lo + 2 * tid + 1] = base + e1;
        hist[2 * tid] = e0; hist[2 * tid + 1] = e1;     // becomes cursor
        if (r == 0 && tid == 0) offt[N] = E;
        __syncthreads();
        ushort* bkt = bucket + (size_t)t * E + base;
        for (int i = tid; i < m; i += 256) {
            unsigned pv = p[i];
            int pos = atomicAdd(&hist[(pv >> 16) & (RW - 1)], 1);
            bkt[pos] = (ushort)(pv & 0xffffu);
        }
        __syncthreads();
    }
    __threadfence();
    grid.sync();

    // ================= phase D: softmax + aggregate =================
    {
        int wid = tid >> 6, lane = tid & 63;
        int h = lane & 7, e8 = lane >> 3;
        int hf = lane >> 5, q = lane & 31;
        int j0 = q * 4, hbase = (q & 1) * 4;
        float* ev = smem + wid * 512;
        for (int v = bid; v < aggItems; v += nb) {
            int t = v & 1, gnode = v >> 1;
            int n = gnode * 4 + wid;
            if (n >= N) continue;
            const int* offt = off + (size_t)t * (N + 1);
            const ushort* bkt = bucket + (size_t)t * E;
            int beg = offt[n], end = offt[n + 1];
            float vh = sv[n * 16 + t * 8 + h];
            float acc0 = 0.f, acc1 = 0.f, acc2 = 0.f, acc3 = 0.f;
            float l = 0.f;
            for (int cbeg = beg; cbeg < end; cbeg += 64) {
                int cnt = min(end - cbeg, 64);
                int gmax = (cnt + 7) >> 3;
                for (int g = 0; g < gmax; ++g) {
                    int e = g * 8 + e8;
                    bool valid = e < cnt;
                    int srcv = 0;
                    if (valid) srcv = bkt[cbeg + e];
                    float sc = su[srcv * 16 + t * 8 + h] + vh;
                    sc = (sc >= 0.f) ? sc : NEG_SLOPE * sc;
                    float eval = valid ? __expf(sc) : 0.f;
                    l += eval;
                    ev[e * 8 + h] = eval;
                }
                int pairs2 = (cnt + 1) >> 1;
                for (int i2 = 0; i2 < pairs2; ++i2) {
                    int eidx = i2 * 2 + hf;
                    int srcv = 0;
                    if (eidx < cnt) srcv = bkt[cbeg + eidx];
                    float4 p4 = *(const float4*)(ev + eidx * 8 + hbase);
                    uint2 u = *(const uint2*)(xbf + (size_t)srcv * 128 + j0);
                    float x0 = __uint_as_float(u.x << 16);
                    float x1 = __uint_as_float(u.x & 0xffff0000u);
                    float x2 = __uint_as_float(u.y << 16);
                    float x3 = __uint_as_float(u.y & 0xffff0000u);
                    acc0 = fmaf(x0, p4.x, acc0);
                    acc1 = fmaf(x1, p4.y, acc1);
                    acc2 = fmaf(x2, p4.z, acc2);
                    acc3 = fmaf(x3, p4.w, acc3);
                }
            }
            l += __shfl_xor(l, 8);
            l += __shfl_xor(l, 16);
            l += __shfl_xor(l, 32);
            float invl = (l > 0.f) ? (1.f / l) : 0.f;
            acc0 += __shfl_xor(acc0, 32);
            acc1 += __shfl_xor(acc1, 32);
            acc2 += __shfl_xor(acc2, 32);
            acc3 += __shfl_xor(acc3, 32);
            float i0 = __shfl(invl, hbase);
            float i1 = __shfl(invl, hbase + 1);
            float i2v = __shfl(invl, hbase + 2);
            float i3 = __shfl(invl, hbase + 3);
            if (hf == 0) {
                float4 r4 = make_float4(acc0 * i0, acc1 * i1, acc2 * i2v, acc3 * i3);
                *(float4*)(out + (size_t)n * 384 + 128 + (size_t)t * 128 + j0) = r4;
            }
        }
    }
}

extern "C" void kernel_launch(void* const* d_in, const int* in_sizes, int n_in,
                              void* d_out, int out_size, void* d_ws, size_t ws_size,
                              hipStream_t stream)
{
    const float* x  = (const float*)d_in[0];
    const float* wu = (const float*)d_in[1];
    const float* bu = (const float*)d_in[2];
    const float* wv = (const float*)d_in[3];
    const int* s0 = (const int*)d_in[4];
    const int* d0 = (const int*)d_in[5];
    const int* s1 = (const int*)d_in[6];
    const int* d1 = (const int*)d_in[7];
    float* out = (float*)d_out;
    int N = in_sizes[0] / 128;
    int E = in_sizes[4];

    int nr = ((N - 1) >> RSHIFT) + 1;               // 98 for N=50000
    long long mean = (long long)RW * E / N;         // ~8192
    int cap = (int)(mean + mean / 4 + 1024);        // ~11264 (>45 sigma)

    char* ws = (char*)d_ws;
    size_t o = 0;
    auto alloc = [&](size_t bytes) -> void* {
        void* p = ws + o;
        o = (o + bytes + 255) & ~(size_t)255;
        return p;
    };
    float* su       = (float*)alloc((size_t)N * 16 * 4);
    float* sv       = (float*)alloc((size_t)N * 16 * 4);
    int* gcur       = (int*)alloc((size_t)2 * nr * 4);
    int* off        = (int*)alloc((size_t)2 * (N + 1) * 4);
    unsigned* pairs = (unsigned*)alloc((size_t)2 * nr * cap * 4);
    ushort* bucket  = (ushort*)alloc((size_t)2 * E * 2);
    ushort* xbf     = (ushort*)alloc((size_t)N * 128 * 2);

    int convItems  = (N * 32 + 2047) / 2048;        // 782
    int scoreItems = (N + 127) / 128;               // 391
    int partItems  = 2 * ((E + CHUNKP - 1) / CHUNKP);  // 782
    int buildItems = 2 * nr;                        // 196
    int aggItems   = 2 * ((N + 3) / 4);             // 25000

    int dev = 0;
    hipGetDevice(&dev);
    int numCU = 0;
    hipDeviceGetAttribute(&numCU, hipDeviceAttributeMultiprocessorCount, dev);
    if (numCU <= 0) numCU = 256;
    int maxB = 0;
    hipOccupancyMaxActiveBlocksPerMultiprocessor(&maxB, fused_kernel, 256, 0);
    if (maxB < 1) maxB = 1;
    if (maxB > 8) maxB = 8;
    int nb = numCU * maxB;
    if (nb > 4096) nb = 4096;

    void* args[] = {
        (void*)&x, (void*)&wu, (void*)&bu, (void*)&wv,
        (void*)&s0, (void*)&d0, (void*)&s1, (void*)&d1,
        (void*)&out, (void*)&xbf, (void*)&su, (void*)&sv,
        (void*)&gcur, (void*)&pairs, (void*)&bucket, (void*)&off,
        (void*)&N, (void*)&E, (void*)&nr, (void*)&cap,
        (void*)&convItems, (void*)&scoreItems, (void*)&partItems,
        (void*)&buildItems, (void*)&aggItems
    };
    hipLaunchCooperativeKernel((const void*)fused_kernel, dim3(nb), dim3(256),
                               args, 0, stream);
}

// Round 7
// 261.758 us; speedup vs baseline: 4.0632x; 4.0632x over previous
//
#include <hip/hip_runtime.h>

#define NEG_SLOPE 0.2f
#define RSHIFT 6       // range width 64 dst nodes -> LDS-resident counting sort
#define RW     64
#define MAXNR  800     // supports N <= 51200
#define CHUNKP 8192    // edges per partition block

__device__ __forceinline__ ushort f2bf(float f) {
    union { float f; unsigned u; } c; c.f = f;
    unsigned u = c.u;
    return (ushort)((u + 0x7fffu + ((u >> 16) & 1u)) >> 16);   // RNE
}

// ---------------- mega: out[:, :128]=x + xbf=bf16(x) | scores | edge partition
__global__ __launch_bounds__(256) void mega_kernel(
    const float* __restrict__ x, const float* __restrict__ wu,
    const float* __restrict__ bu, const float* __restrict__ wv,
    const int* __restrict__ s0, const int* __restrict__ d0,
    const int* __restrict__ s1, const int* __restrict__ d1,
    float* __restrict__ out, ushort* __restrict__ xbf,
    float* __restrict__ su, float* __restrict__ sv,
    int* __restrict__ gcur, unsigned* __restrict__ pairs,
    int N, int E, int nr, int cap, int convBlocks, int scoreBlocks, int ppset)
{
    __shared__ float wlds[32 * 129];          // 16.5 KB, also aliased by partition
    int* smi = (int*)wlds;
    int tid = threadIdx.x;
    int bid = blockIdx.x;

    if (bid < convBlocks) {                   // ---- role A: copy + bf16 convert
        int i = bid * 256 + tid;
        if (i < N * 32) {
            float4 v = ((const float4*)x)[i];
            int n = i >> 5, q = i & 31;
            ((float4*)out)[(size_t)n * 96 + q] = v;
            ushort4 b;
            b.x = f2bf(v.x); b.y = f2bf(v.y); b.z = f2bf(v.z); b.w = f2bf(v.w);
            *(ushort4*)(xbf + (size_t)i * 4) = b;
        }
        return;
    }
    if (bid < convBlocks + scoreBlocks) {     // ---- role B: scores (R5-proven)
        for (int i = tid; i < 4096; i += 256) {
            int o = i >> 7, k = i & 127;
            wlds[o * 129 + k] = (o < 16) ? wu[i] : wv[i - 2048];
        }
        __syncthreads();
        int o = tid & 15;
        int n = (bid - convBlocks) * 16 + (tid >> 4);
        if (n >= N) return;
        const float4* xr4 = (const float4*)(x + (size_t)n * 128);
        const float* wur = wlds + o * 129;
        const float* wvr = wlds + (16 + o) * 129;
        float au = 0.f, av = 0.f;
#pragma unroll
        for (int kk = 0; kk < 32; ++kk) {
            float4 xv = xr4[kk];
            int k = kk * 4;
            au = fmaf(xv.x, wur[k],     au);  av = fmaf(xv.x, wvr[k],     av);
            au = fmaf(xv.y, wur[k + 1], au);  av = fmaf(xv.y, wvr[k + 1], av);
            au = fmaf(xv.z, wur[k + 2], au);  av = fmaf(xv.z, wvr[k + 2], av);
            au = fmaf(xv.w, wur[k + 3], au);  av = fmaf(xv.w, wvr[k + 3], av);
        }
        su[n * 16 + o] = au + bu[o];
        sv[n * 16 + o] = av;
        return;
    }
    // ---- role C: partition edges into per-(set,range) (dst<<16|src) segments
    int pb = bid - convBlocks - scoreBlocks;
    int t = pb / ppset, c = pb % ppset;
    const int* ss = t ? s1 : s0;
    const int* dd = t ? d1 : d0;
    int beg = c * CHUNKP, end = min(E, beg + CHUNKP);
    int* lcnt = smi; int* gb = smi + MAXNR; int* lrun = smi + 2 * MAXNR;
    for (int i = tid; i < nr; i += 256) lcnt[i] = 0;
    __syncthreads();
    for (int e = beg + tid; e < end; e += 256)
        atomicAdd(&lcnt[dd[e] >> RSHIFT], 1);
    __syncthreads();
    for (int i = tid; i < nr; i += 256) {
        gb[i] = atomicAdd(&gcur[t * nr + i], lcnt[i]);
        lrun[i] = 0;
    }
    __syncthreads();
    unsigned* pt = pairs + (size_t)t * nr * cap;
    for (int e = beg + tid; e < end; e += 256) {
        int dst = dd[e], src = ss[e];
        int r = dst >> RSHIFT;
        int pos = atomicAdd(&lrun[r], 1);
        pt[(size_t)r * cap + gb[r] + pos] = ((unsigned)dst << 16) | (unsigned)src;
    }
}

// ---------------- buildagg: per-(range,set) block. LDS counting-sort of the
// range's ~1024 edges (bucket/off/cursor never hit global), then per-node
// single-pass softmax + gather-aggregate. No cross-block dependency.
__global__ __launch_bounds__(256, 8) void buildagg_kernel(
    const ushort* __restrict__ xbf, const float* __restrict__ su,
    const float* __restrict__ sv, const int* __restrict__ gcur,
    const unsigned* __restrict__ pairs, float* __restrict__ out,
    int N, int E, int nr, int cap)
{
    __shared__ ushort srcs[1408];             // sorted src ids (cap <= 1344)
    __shared__ int offl[65];
    __shared__ int cursor[64];
    __shared__ __align__(16) float ev4[4][512];
    int r = blockIdx.x, t = blockIdx.y, tid = threadIdx.x;
    int m = gcur[t * nr + r];
    if (m > cap) m = cap;                     // safety (never expected)
    const unsigned* p = pairs + ((size_t)t * nr + r) * cap;

    if (tid < 64) cursor[tid] = 0;
    __syncthreads();
    for (int i = tid; i < m; i += 256)        // pass 1: histogram (local node id)
        atomicAdd(&cursor[(p[i] >> 16) & (RW - 1)], 1);
    __syncthreads();
    if (tid < 64) {                           // 64-wide shfl scan -> offsets
        int v = cursor[tid];
        int incl = v;
#pragma unroll
        for (int d = 1; d < 64; d <<= 1) {
            int o = __shfl(incl, tid - d);
            if (tid >= d) incl += o;
        }
        offl[tid + 1] = incl;
        if (tid == 0) offl[0] = 0;
        cursor[tid] = incl - v;               // exclusive -> scatter cursor
    }
    __syncthreads();
    for (int i = tid; i < m; i += 256) {      // pass 2: scatter into LDS bucket
        unsigned v = p[i];
        int pos = atomicAdd(&cursor[(v >> 16) & (RW - 1)], 1);
        srcs[pos] = (ushort)(v & 0xffffu);
    }
    __syncthreads();

    // ---- agg: wave w handles local nodes w, w+4, ...
    int wid = tid >> 6, lane = tid & 63;
    int h = lane & 7, e8 = lane >> 3;
    int hf = lane >> 5, q = lane & 31;
    int j0 = q * 4, hbase = (q & 1) * 4;
    float* ev = ev4[wid];
    for (int ln = wid; ln < RW; ln += 4) {
        int n = (r << RSHIFT) + ln;
        if (n >= N) break;
        int beg = offl[ln], end = offl[ln + 1];
        float vh = sv[n * 16 + t * 8 + h];
        float acc0 = 0.f, acc1 = 0.f, acc2 = 0.f, acc3 = 0.f;
        float l = 0.f;
        for (int cbeg = beg; cbeg < end; cbeg += 64) {
            int cnt = min(end - cbeg, 64);
            int gmax = (cnt + 7) >> 3;
            for (int g = 0; g < gmax; ++g) {  // e-phase: 8 edges x 8 heads
                int e = g * 8 + e8;
                bool valid = e < cnt;
                int srcv = srcs[cbeg + (valid ? e : 0)];
                float sc = su[srcv * 16 + t * 8 + h] + vh;
                sc = (sc >= 0.f) ? sc : NEG_SLOPE * sc;
                float ee = valid ? __expf(sc) : 0.f;
                l += ee;
                ev[e * 8 + h] = ee;
            }
            int pairs2 = (cnt + 1) >> 1;
            for (int i2 = 0; i2 < pairs2; ++i2) {  // acc: 2 edges/iter
                int eidx = i2 * 2 + hf;
                int srcv = srcs[cbeg + ((eidx < cnt) ? eidx : 0)];
                float4 p4 = *(const float4*)(ev + eidx * 8 + hbase);
                uint2 u = *(const uint2*)(xbf + (size_t)srcv * 128 + j0);
                float x0 = __uint_as_float(u.x << 16);
                float x1 = __uint_as_float(u.x & 0xffff0000u);
                float x2 = __uint_as_float(u.y << 16);
                float x3 = __uint_as_float(u.y & 0xffff0000u);
                acc0 = fmaf(x0, p4.x, acc0);
                acc1 = fmaf(x1, p4.y, acc1);
                acc2 = fmaf(x2, p4.z, acc2);
                acc3 = fmaf(x3, p4.w, acc3);
            }
        }
        l += __shfl_xor(l, 8);
        l += __shfl_xor(l, 16);
        l += __shfl_xor(l, 32);
        float invl = (l > 0.f) ? (1.f / l) : 0.f;
        acc0 += __shfl_xor(acc0, 32);
        acc1 += __shfl_xor(acc1, 32);
        acc2 += __shfl_xor(acc2, 32);
        acc3 += __shfl_xor(acc3, 32);
        float i0 = __shfl(invl, hbase);
        float i1 = __shfl(invl, hbase + 1);
        float i2v = __shfl(invl, hbase + 2);
        float i3 = __shfl(invl, hbase + 3);
        if (hf == 0) {
            float4 r4 = make_float4(acc0 * i0, acc1 * i1, acc2 * i2v, acc3 * i3);
            *(float4*)(out + (size_t)n * 384 + 128 + (size_t)t * 128 + j0) = r4;
        }
    }
}

extern "C" void kernel_launch(void* const* d_in, const int* in_sizes, int n_in,
                              void* d_out, int out_size, void* d_ws, size_t ws_size,
                              hipStream_t stream)
{
    const float* x  = (const float*)d_in[0];
    const float* wu = (const float*)d_in[1];
    const float* bu = (const float*)d_in[2];
    const float* wv = (const float*)d_in[3];
    const int* s0 = (const int*)d_in[4];
    const int* d0 = (const int*)d_in[5];
    const int* s1 = (const int*)d_in[6];
    const int* d1 = (const int*)d_in[7];
    float* out = (float*)d_out;
    int N = in_sizes[0] / 128;
    int E = in_sizes[4];

    int nr = ((N - 1) >> RSHIFT) + 1;               // 782 for N=50000 (<= MAXNR)
    long long mean = (long long)RW * E / N;         // ~1024
    int cap = (int)(mean + mean / 4 + 64);          // 1344 (>9 sigma margin)

    char* ws = (char*)d_ws;
    size_t o = 0;
    auto alloc = [&](size_t bytes) -> void* {
        void* p = ws + o;
        o = (o + bytes + 255) & ~(size_t)255;
        return p;
    };
    float* su       = (float*)alloc((size_t)N * 16 * 4);
    float* sv       = (float*)alloc((size_t)N * 16 * 4);
    int* gcur       = (int*)alloc((size_t)2 * nr * 4);
    unsigned* pairs = (unsigned*)alloc((size_t)2 * nr * cap * 4);
    ushort* xbf     = (ushort*)alloc((size_t)N * 128 * 2);

    int convBlocks  = (N * 32 + 255) / 256;         // 6250
    int scoreBlocks = (N + 15) / 16;                // 3125
    int ppset       = (E + CHUNKP - 1) / CHUNKP;    // 98

    hipMemsetAsync(gcur, 0, (size_t)2 * nr * 4, stream);
    mega_kernel<<<convBlocks + scoreBlocks + 2 * ppset, 256, 0, stream>>>(
        x, wu, bu, wv, s0, d0, s1, d1, out, xbf, su, sv,
        gcur, pairs, N, E, nr, cap, convBlocks, scoreBlocks, ppset);
    buildagg_kernel<<<dim3(nr, 2), 256, 0, stream>>>(
        xbf, su, sv, gcur, pairs, out, N, E, nr, cap);
}